// Round 5
// baseline (143.182 us; speedup 1.0000x reference)
//
#include <hip/hip_runtime.h>

#define N_INST 4096
#define D_FEAT 512
#define NHEAD 8
#define NPAIR 131072

typedef __attribute__((ext_vector_type(8))) short short8;
typedef __attribute__((ext_vector_type(4))) float f32x4;

__device__ inline unsigned short f2bf(float f) {
  union { float f; unsigned u; } v; v.f = f;
  unsigned r = v.u + 0x7fffu + ((v.u >> 16) & 1u);
  return (unsigned short)(r >> 16);
}
__device__ inline float bf2f(unsigned short b) {
  union { unsigned u; float f; } v; v.u = ((unsigned)b) << 16; return v.f;
}
__device__ inline void gload16(const void* g, void* l) {
  __builtin_amdgcn_global_load_lds((const __attribute__((address_space(1))) unsigned int*)g,
                                   (__attribute__((address_space(3))) unsigned int*)l, 16, 0, 0);
}

// ---------------- cast f32 -> bf16 ----------------
__global__ __launch_bounds__(256) void k_cast(const float* __restrict__ src,
                                              unsigned short* __restrict__ dst, int n) {
  int i = (blockIdx.x * 256 + threadIdx.x) * 4;
  if (i >= n) return;
  float4 v = *(const float4*)&src[i];
  ushort4 o;
  o.x = f2bf(v.x); o.y = f2bf(v.y); o.z = f2bf(v.z); o.w = f2bf(v.w);
  *(ushort4*)&dst[i] = o;
}

// ---------------- x (4096x512 f32) -> xb bf16 AND xT bf16 (512x4096), one read ----------------
__global__ __launch_bounds__(256) void k_xprep(const float* __restrict__ x,
                                               unsigned short* __restrict__ xb,
                                               unsigned short* __restrict__ xT) {
  __shared__ float t[32][33];
  int bx = blockIdx.x, by = blockIdx.y;
  int tx = threadIdx.x & 31, ty = threadIdx.x >> 5;
  #pragma unroll
  for (int r = 0; r < 4; ++r) {
    int row = by * 32 + ty + r * 8;
    float v = x[(size_t)row * D_FEAT + bx * 32 + tx];
    t[ty + r * 8][tx] = v;
    xb[(size_t)row * D_FEAT + bx * 32 + tx] = f2bf(v);
  }
  __syncthreads();
  #pragma unroll
  for (int r = 0; r < 4; ++r)
    xT[(size_t)(bx * 32 + ty + r * 8) * N_INST + by * 32 + tx] = f2bf(t[tx][ty + r * 8]);
}

// ---------------- wave-per-row: 0/1 bf16 mask (diag=1) + off-diag nonzero count ----------------
// Explicit 8-deep load batching: v[8] register array forces 8 outstanding
// global loads per wave (R4 post-mortem: VGPR=12 -> 1 in flight -> latency-bound).
__global__ __launch_bounds__(256) void k_mask_acnt(const float* __restrict__ agg,
                                                   unsigned short* __restrict__ maskb,
                                                   int* __restrict__ acnt) {
  int row = blockIdx.x * 4 + (threadIdx.x >> 6);
  int lane = threadIdx.x & 63;
  const float4* r4 = (const float4*)(agg + (size_t)row * N_INST);
  ushort4* m4 = (ushort4*)(maskb + (size_t)row * N_INST);
  int cnt = 0;
  #pragma unroll
  for (int half = 0; half < 2; ++half) {
    float4 v[8];
    #pragma unroll
    for (int u = 0; u < 8; ++u)
      v[u] = r4[(half * 8 + u) * 64 + lane];
    #pragma unroll
    for (int u = 0; u < 8; ++u) {
      int t = (half * 8 + u) * 64 + lane;
      ushort4 m;
      m.x = (v[u].x != 0.f) ? 0x3F80 : 0;
      m.y = (v[u].y != 0.f) ? 0x3F80 : 0;
      m.z = (v[u].z != 0.f) ? 0x3F80 : 0;
      m.w = (v[u].w != 0.f) ? 0x3F80 : 0;
      cnt += (v[u].x != 0.f) + (v[u].y != 0.f) + (v[u].z != 0.f) + (v[u].w != 0.f);
      int j = t * 4;
      if (row >= j && row < j + 4) {
        int d = row - j;
        ((unsigned short*)&m)[d] = 0x3F80;            // diagonal always present
        cnt -= (((const float*)&v[u])[d] != 0.f);     // diag not counted as generic
      }
      m4[t] = m;
    }
  }
  #pragma unroll
  for (int msk = 1; msk < 64; msk <<= 1) cnt += __shfl_xor(cnt, msk);
  if (lane == 0) acnt[row] = cnt;
}

// ---------------- NT bf16 MFMA GEMM, BM=128 BN=64 BK=64, gload_lds + dbuf + swizzle ----------------
// XCD-chunked tile swizzle: blocks resident on one XCD cover contiguous tiles
// (4 A-panels + all B panels ~= one XCD's 4MB L2), killing the panel re-fetch.
template<int BIAS, int CBF16>
__global__ __launch_bounds__(256, 2) void k_gemm(const unsigned short* __restrict__ A,
                                                 const unsigned short* __restrict__ B,
                                                 const float* __restrict__ bias0,
                                                 const float* __restrict__ bias1,
                                                 void* __restrict__ Cv,
                                                 int M, int N, int K, int klen) {
  __shared__ __align__(16) unsigned short lA[2][128 * 64];
  __shared__ __align__(16) unsigned short lB[2][64 * 64];
  int tid = threadIdx.x, wave = tid >> 6, lane = tid & 63;
  int wm = wave & 1, wn = wave >> 1;
  // --- XCD-chunked bijective swizzle (nxy % 8 == 0 for all our grids) ---
  int gx = gridDim.x;
  int nxy = gx * gridDim.y;
  int lin = blockIdx.x + gx * blockIdx.y;
  int nch = nxy >> 3;
  int nl = (lin & 7) * nch + (lin >> 3);
  int bx = nl % gx, by = nl / gx;
  int bm = by * 128, bn = bx * 64;
  int kbase = blockIdx.z * klen;
  // staging: 1KB chunks = 8 rows x 128B; lane l -> row +l>>3, phys granule l&7.
  // swizzled layout stores logical granule g at phys g^(row&7) -> source granule = (l&7)^(l>>3)
  int srow = lane >> 3;
  int sg = (lane & 7) ^ srow;
  const unsigned short* ag[4];
  const unsigned short* bg[2];
  #pragma unroll
  for (int p = 0; p < 4; ++p) {
    int row = (wave * 4 + p) * 8 + srow;
    ag[p] = A + (size_t)(bm + row) * K + kbase + sg * 8;
  }
  #pragma unroll
  for (int p = 0; p < 2; ++p) {
    int row = (wave * 2 + p) * 8 + srow;
    bg[p] = B + (size_t)(bn + row) * K + kbase + sg * 8;
  }
  auto stage = [&](int buf) {
    #pragma unroll
    for (int p = 0; p < 4; ++p) { gload16(ag[p], &lA[buf][(wave * 4 + p) * 512]); ag[p] += 64; }
    #pragma unroll
    for (int p = 0; p < 2; ++p) { gload16(bg[p], &lB[buf][(wave * 2 + p) * 512]); bg[p] += 64; }
  };
  f32x4 acc[4][2] = {};
  int nt = klen / 64;
  stage(0);
  __syncthreads();
  int cur = 0;
  int lrow = lane & 15, glq = lane >> 4;
  for (int t = 0; t < nt; ++t) {
    if (t + 1 < nt) stage(cur ^ 1);
    short8 bf[2][2];
    #pragma unroll
    for (int kk = 0; kk < 2; ++kk)
      #pragma unroll
      for (int ni = 0; ni < 2; ++ni) {
        int row = wn * 32 + ni * 16 + lrow;
        int pg = (kk * 4 + glq) ^ (row & 7);
        bf[kk][ni] = *(const short8*)&lB[cur][row * 64 + pg * 8];
      }
    #pragma unroll
    for (int mi = 0; mi < 4; ++mi)
      #pragma unroll
      for (int kk = 0; kk < 2; ++kk) {
        int row = wm * 64 + mi * 16 + lrow;
        int pg = (kk * 4 + glq) ^ (row & 7);
        short8 af = *(const short8*)&lA[cur][row * 64 + pg * 8];
        #pragma unroll
        for (int ni = 0; ni < 2; ++ni)
          acc[mi][ni] = __builtin_amdgcn_mfma_f32_16x16x32_bf16(af, bf[kk][ni], acc[mi][ni], 0, 0, 0);
      }
    __syncthreads();
    cur ^= 1;
  }
  #pragma unroll
  for (int mi = 0; mi < 4; ++mi)
    #pragma unroll
    for (int ni = 0; ni < 2; ++ni) {
      int col = bn + wn * 32 + ni * 16 + lrow;
      float bv = 0.f;
      if (BIAS) bv = (col < 512) ? bias0[col] : bias1[col - 512];
      #pragma unroll
      for (int j = 0; j < 4; ++j) {
        int row = bm + wm * 64 + mi * 16 + glq * 4 + j;
        float vv = acc[mi][ni][j] + bv;
        if (CBF16) {
          ((unsigned short*)Cv)[(size_t)row * N + col] = f2bf(vv);
        } else {
          float* C = (float*)Cv + (size_t)blockIdx.z * M * N;
          C[(size_t)row * N + col] = vv;
        }
      }
    }
}

// ---------------- per-pair exp(score) from fused bf16 QK table ----------------
__global__ __launch_bounds__(256) void k_scores(const unsigned short* __restrict__ QKb,
                                                const int* __restrict__ pairs,
                                                const float* __restrict__ agg,
                                                float* __restrict__ es,
                                                float* __restrict__ sumexp,
                                                int* __restrict__ scnt) {
  int wave = threadIdx.x >> 6, lane = threadIdx.x & 63;
  int e = blockIdx.x * 4 + wave;
  int sub = pairs[2 * e], obj = pairs[2 * e + 1];
  short8 q8 = *(const short8*)&QKb[(size_t)sub * 1024 + lane * 8];
  short8 k8 = *(const short8*)&QKb[(size_t)obj * 1024 + 512 + lane * 8];
  float p = 0.f;
  #pragma unroll
  for (int j = 0; j < 8; ++j)
    p += bf2f((unsigned short)q8[j]) * bf2f((unsigned short)k8[j]);
  p += __shfl_xor(p, 1);
  p += __shfl_xor(p, 2);
  p += __shfl_xor(p, 4);
  float ev = expf(p * 0.125f);   // / sqrt(64)
  bool valid = (sub != obj) && (agg[(size_t)sub * N_INST + obj] != 0.f);
  int h = lane >> 3;
  if ((lane & 7) == 0) {
    es[(size_t)e * 8 + h] = valid ? ev : -1.f;
    if (valid) atomicAdd(&sumexp[sub * 8 + h], ev);
  }
  if (lane == 0 && valid) atomicAdd(&scnt[sub], 1);
}

// ---------------- per-row denominators -> invden, base ----------------
__global__ __launch_bounds__(256) void k_denom(const float* __restrict__ sumexp,
                                               const int* __restrict__ scnt,
                                               const int* __restrict__ acnt,
                                               float* __restrict__ invden,
                                               float* __restrict__ base) {
  int i = blockIdx.x * 256 + threadIdx.x;
  if (i >= N_INST) return;
  float c0 = (float)(acnt[i] - scnt[i]);
  const float E0 = expf(1e-7f);
  float bsum = 0.f;
  #pragma unroll
  for (int h = 0; h < NHEAD; ++h) {
    float inv = 1.0f / (E0 + c0 + sumexp[i * NHEAD + h]);
    invden[i * NHEAD + h] = inv;
    bsum += inv;
  }
  base[i] = bsum * (1.0f / NHEAD);
}

// ---------------- scatter ratio entries into mask ----------------
__global__ __launch_bounds__(256) void k_scatter(const int* __restrict__ pairs,
                                                 const float* __restrict__ es,
                                                 const float* __restrict__ invden,
                                                 const float* __restrict__ base,
                                                 unsigned short* __restrict__ maskb) {
  int e = blockIdx.x * 256 + threadIdx.x;
  if (e >= NPAIR) return;
  float4 e0 = *(const float4*)&es[(size_t)e * 8];
  if (e0.x < 0.f) return;
  float4 e1 = *(const float4*)&es[(size_t)e * 8 + 4];
  int sub = pairs[2 * e], obj = pairs[2 * e + 1];
  const float* inv = &invden[sub * 8];
  float f = e0.x * inv[0] + e0.y * inv[1] + e0.z * inv[2] + e0.w * inv[3] +
            e1.x * inv[4] + e1.y * inv[5] + e1.z * inv[6] + e1.w * inv[7];
  maskb[(size_t)sub * N_INST + obj] = f2bf(f * 0.125f / base[sub]);
}

// ---------------- reduce split-K partials + row scale ----------------
__global__ __launch_bounds__(256) void k_redscale(const float* __restrict__ P,
                                                  const float* __restrict__ base,
                                                  float* __restrict__ out) {
  size_t idx = ((size_t)blockIdx.x * 256 + threadIdx.x) * 4;
  int i = (int)(idx >> 9);
  float4 a = *(const float4*)&P[idx];
  float4 b = *(const float4*)&P[idx + (size_t)N_INST * 512];
  float s = base[i];
  float4 o;
  o.x = s * (a.x + b.x); o.y = s * (a.y + b.y);
  o.z = s * (a.z + b.z); o.w = s * (a.w + b.w);
  *(float4*)&out[idx] = o;
}

extern "C" void kernel_launch(void* const* d_in, const int* in_sizes, int n_in,
                              void* d_out, int out_size, void* d_ws, size_t ws_size,
                              hipStream_t stream) {
  const float* x   = (const float*)d_in[0];
  const float* agg = (const float*)d_in[1];
  const int*   prs = (const int*)d_in[2];
  const float* w_q = (const float*)d_in[3];
  const float* b_q = (const float*)d_in[4];
  const float* w_k = (const float*)d_in[5];
  const float* b_k = (const float*)d_in[6];
  float* out = (float*)d_out;

  char* ws = (char*)d_ws;
  size_t off = 0;
  auto alloc = [&](size_t bytes) -> void* {
    void* p = ws + off;
    off += (bytes + 255) & ~(size_t)255;
    return p;
  };
  unsigned short* xb    = (unsigned short*)alloc((size_t)N_INST * D_FEAT * 2);
  unsigned short* xbT   = (unsigned short*)alloc((size_t)D_FEAT * N_INST * 2);
  unsigned short* wqkb  = (unsigned short*)alloc((size_t)1024 * D_FEAT * 2);
  void*           QKP   = alloc((size_t)N_INST * 1024 * 4);   // bf16 QK table, later f32 split-K partials
  float*          es    = (float*)alloc((size_t)NPAIR * NHEAD * 4);
  float*          sumexp= (float*)alloc((size_t)N_INST * NHEAD * 4);
  int*            scnt  = (int*)alloc((size_t)N_INST * 4);
  int*            acnt  = (int*)alloc((size_t)N_INST * 4);
  float*          invden= (float*)alloc((size_t)N_INST * NHEAD * 4);
  float*          base  = (float*)alloc((size_t)N_INST * 4);
  unsigned short* maskb = (unsigned short*)alloc((size_t)N_INST * N_INST * 2);

  hipMemsetAsync(sumexp, 0, (size_t)N_INST * NHEAD * 4, stream);
  hipMemsetAsync(scnt, 0, (size_t)N_INST * 4, stream);

  k_cast<<<dim3(D_FEAT * D_FEAT / 4 / 256), 256, 0, stream>>>(w_q, wqkb, D_FEAT * D_FEAT);
  k_cast<<<dim3(D_FEAT * D_FEAT / 4 / 256), 256, 0, stream>>>(w_k, wqkb + D_FEAT * D_FEAT, D_FEAT * D_FEAT);
  k_xprep<<<dim3(D_FEAT / 32, N_INST / 32), 256, 0, stream>>>(x, xb, xbT);
  k_mask_acnt<<<dim3(N_INST / 4), 256, 0, stream>>>(agg, maskb, acnt);

  // fused Q|K projection: C (4096x1024 bf16) = xb (4096x512) * wqkb (1024x512)^T + bias
  k_gemm<1, 1><<<dim3(1024 / 64, N_INST / 128, 1), 256, 0, stream>>>(
      xb, wqkb, b_q, b_k, QKP, N_INST, 1024, D_FEAT, D_FEAT);

  k_scores<<<dim3(NPAIR / 4), 256, 0, stream>>>((const unsigned short*)QKP, prs, agg, es, sumexp, scnt);
  k_denom<<<dim3(N_INST / 256), 256, 0, stream>>>(sumexp, scnt, acnt, invden, base);
  k_scatter<<<dim3(NPAIR / 256), 256, 0, stream>>>(prs, es, invden, base, maskb);

  // out partials (f32) = maskb (4096x4096) * xbT (512x4096)^T, split-K=2
  k_gemm<0, 0><<<dim3(512 / 64, N_INST / 128, 2), 256, 0, stream>>>(
      maskb, xbT, nullptr, nullptr, QKP, N_INST, 512, N_INST, N_INST / 2);

  k_redscale<<<dim3(N_INST * 512 / 4 / 256), 256, 0, stream>>>((const float*)QKP, base, out);
}

// Round 7
// 134.047 us; speedup vs baseline: 1.0681x; 1.0681x over previous
//
#include <hip/hip_runtime.h>

#define N_INST 4096
#define D_FEAT 512
#define NHEAD 8
#define NPAIR 131072

typedef __attribute__((ext_vector_type(8))) short short8;
typedef __attribute__((ext_vector_type(4))) float f32x4;
typedef __attribute__((ext_vector_type(4))) unsigned short u16x4;

__device__ inline unsigned short f2bf(float f) {
  union { float f; unsigned u; } v; v.f = f;
  unsigned r = v.u + 0x7fffu + ((v.u >> 16) & 1u);
  return (unsigned short)(r >> 16);
}
__device__ inline float bf2f(unsigned short b) {
  union { unsigned u; float f; } v; v.u = ((unsigned)b) << 16; return v.f;
}
__device__ inline void gload16(const void* g, void* l) {
  __builtin_amdgcn_global_load_lds((const __attribute__((address_space(1))) unsigned int*)g,
                                   (__attribute__((address_space(3))) unsigned int*)l, 16, 0, 0);
}

// ---------------- both weight casts in one launch (y=0 -> w_q, y=1 -> w_k) ----------------
__global__ __launch_bounds__(256) void k_castw(const float* __restrict__ wq,
                                               const float* __restrict__ wk,
                                               unsigned short* __restrict__ dst) {
  const float* src = blockIdx.y ? wk : wq;
  unsigned short* d = dst + (size_t)blockIdx.y * D_FEAT * D_FEAT;
  int i = (blockIdx.x * 256 + threadIdx.x) * 4;
  float4 v = *(const float4*)&src[i];
  ushort4 o;
  o.x = f2bf(v.x); o.y = f2bf(v.y); o.z = f2bf(v.z); o.w = f2bf(v.w);
  *(ushort4*)&d[i] = o;
}

// ---------------- x (4096x512 f32) -> xb bf16 AND xT bf16 (512x4096), one read ----------------
__global__ __launch_bounds__(256) void k_xprep(const float* __restrict__ x,
                                               unsigned short* __restrict__ xb,
                                               unsigned short* __restrict__ xT) {
  __shared__ float t[32][33];
  int bx = blockIdx.x, by = blockIdx.y;
  int tx = threadIdx.x & 31, ty = threadIdx.x >> 5;
  #pragma unroll
  for (int r = 0; r < 4; ++r) {
    int row = by * 32 + ty + r * 8;
    float v = x[(size_t)row * D_FEAT + bx * 32 + tx];
    t[ty + r * 8][tx] = v;
    xb[(size_t)row * D_FEAT + bx * 32 + tx] = f2bf(v);
  }
  __syncthreads();
  #pragma unroll
  for (int r = 0; r < 4; ++r)
    xT[(size_t)(bx * 32 + ty + r * 8) * N_INST + by * 32 + tx] = f2bf(t[tx][ty + r * 8]);
}

// ---------------- block-per-row (R3 structure): 0/1 bf16 mask (diag=1) + off-diag count ----------------
// 4-deep explicit load batch (modest MLP; R5's 8-deep thrashed L2 -> 3x write
// amplification). Nontemporal load/store: streaming data bypasses L2 allocate.
// ext_vector_type (clang vectors) required by the nontemporal builtins.
__global__ __launch_bounds__(256) void k_mask_acnt(const float* __restrict__ agg,
                                                   unsigned short* __restrict__ maskb,
                                                   int* __restrict__ acnt) {
  int i = blockIdx.x;
  const f32x4* row = (const f32x4*)(agg + (size_t)i * N_INST);
  u16x4* mrow = (u16x4*)(maskb + (size_t)i * N_INST);
  int tid = threadIdx.x;
  f32x4 v[4];
  #pragma unroll
  for (int u = 0; u < 4; ++u)
    v[u] = __builtin_nontemporal_load(&row[u * 256 + tid]);
  int cnt = 0;
  #pragma unroll
  for (int u = 0; u < 4; ++u) {
    int t = u * 256 + tid;
    u16x4 m;
    m[0] = (v[u][0] != 0.f) ? 0x3F80 : 0;
    m[1] = (v[u][1] != 0.f) ? 0x3F80 : 0;
    m[2] = (v[u][2] != 0.f) ? 0x3F80 : 0;
    m[3] = (v[u][3] != 0.f) ? 0x3F80 : 0;
    cnt += (v[u][0] != 0.f) + (v[u][1] != 0.f) + (v[u][2] != 0.f) + (v[u][3] != 0.f);
    int j = t * 4;
    if (i >= j && i < j + 4) {
      int d = i - j;
      m[d] = 0x3F80;                    // diagonal always present
      cnt -= (v[u][d] != 0.f);          // diag not counted as generic
    }
    __builtin_nontemporal_store(m, &mrow[t]);
  }
  #pragma unroll
  for (int msk = 1; msk < 64; msk <<= 1) cnt += __shfl_xor(cnt, msk);
  __shared__ int wsum[4];
  if ((threadIdx.x & 63) == 0) wsum[threadIdx.x >> 6] = cnt;
  __syncthreads();
  if (threadIdx.x == 0) acnt[i] = wsum[0] + wsum[1] + wsum[2] + wsum[3];
}

// ---------------- NT bf16 MFMA GEMM, BM=128 BN=64 BK=64, gload_lds + dbuf + swizzle ----------------
// XCD-chunked tile swizzle: blocks resident on one XCD cover contiguous tiles
// (4 A-panels + all B panels ~= one XCD's 4MB L2), killing the panel re-fetch.
template<int BIAS, int CBF16>
__global__ __launch_bounds__(256, 2) void k_gemm(const unsigned short* __restrict__ A,
                                                 const unsigned short* __restrict__ B,
                                                 const float* __restrict__ bias0,
                                                 const float* __restrict__ bias1,
                                                 void* __restrict__ Cv,
                                                 int M, int N, int K, int klen) {
  __shared__ __align__(16) unsigned short lA[2][128 * 64];
  __shared__ __align__(16) unsigned short lB[2][64 * 64];
  int tid = threadIdx.x, wave = tid >> 6, lane = tid & 63;
  int wm = wave & 1, wn = wave >> 1;
  // --- XCD-chunked bijective swizzle (nxy % 8 == 0 for all our grids) ---
  int gx = gridDim.x;
  int nxy = gx * gridDim.y;
  int lin = blockIdx.x + gx * blockIdx.y;
  int nch = nxy >> 3;
  int nl = (lin & 7) * nch + (lin >> 3);
  int bx = nl % gx, by = nl / gx;
  int bm = by * 128, bn = bx * 64;
  int kbase = blockIdx.z * klen;
  // staging: 1KB chunks = 8 rows x 128B; lane l -> row +l>>3, phys granule l&7.
  // swizzled layout stores logical granule g at phys g^(row&7) -> source granule = (l&7)^(l>>3)
  int srow = lane >> 3;
  int sg = (lane & 7) ^ srow;
  const unsigned short* ag[4];
  const unsigned short* bg[2];
  #pragma unroll
  for (int p = 0; p < 4; ++p) {
    int row = (wave * 4 + p) * 8 + srow;
    ag[p] = A + (size_t)(bm + row) * K + kbase + sg * 8;
  }
  #pragma unroll
  for (int p = 0; p < 2; ++p) {
    int row = (wave * 2 + p) * 8 + srow;
    bg[p] = B + (size_t)(bn + row) * K + kbase + sg * 8;
  }
  auto stage = [&](int buf) {
    #pragma unroll
    for (int p = 0; p < 4; ++p) { gload16(ag[p], &lA[buf][(wave * 4 + p) * 512]); ag[p] += 64; }
    #pragma unroll
    for (int p = 0; p < 2; ++p) { gload16(bg[p], &lB[buf][(wave * 2 + p) * 512]); bg[p] += 64; }
  };
  f32x4 acc[4][2] = {};
  int nt = klen / 64;
  stage(0);
  __syncthreads();
  int cur = 0;
  int lrow = lane & 15, glq = lane >> 4;
  for (int t = 0; t < nt; ++t) {
    if (t + 1 < nt) stage(cur ^ 1);
    short8 bf[2][2];
    #pragma unroll
    for (int kk = 0; kk < 2; ++kk)
      #pragma unroll
      for (int ni = 0; ni < 2; ++ni) {
        int row = wn * 32 + ni * 16 + lrow;
        int pg = (kk * 4 + glq) ^ (row & 7);
        bf[kk][ni] = *(const short8*)&lB[cur][row * 64 + pg * 8];
      }
    #pragma unroll
    for (int mi = 0; mi < 4; ++mi)
      #pragma unroll
      for (int kk = 0; kk < 2; ++kk) {
        int row = wm * 64 + mi * 16 + lrow;
        int pg = (kk * 4 + glq) ^ (row & 7);
        short8 af = *(const short8*)&lA[cur][row * 64 + pg * 8];
        #pragma unroll
        for (int ni = 0; ni < 2; ++ni)
          acc[mi][ni] = __builtin_amdgcn_mfma_f32_16x16x32_bf16(af, bf[kk][ni], acc[mi][ni], 0, 0, 0);
      }
    __syncthreads();
    cur ^= 1;
  }
  #pragma unroll
  for (int mi = 0; mi < 4; ++mi)
    #pragma unroll
    for (int ni = 0; ni < 2; ++ni) {
      int col = bn + wn * 32 + ni * 16 + lrow;
      float bv = 0.f;
      if (BIAS) bv = (col < 512) ? bias0[col] : bias1[col - 512];
      #pragma unroll
      for (int j = 0; j < 4; ++j) {
        int row = bm + wm * 64 + mi * 16 + glq * 4 + j;
        float vv = acc[mi][ni][j] + bv;
        if (CBF16) {
          ((unsigned short*)Cv)[(size_t)row * N + col] = f2bf(vv);
        } else {
          float* C = (float*)Cv + (size_t)blockIdx.z * M * N;
          C[(size_t)row * N + col] = vv;
        }
      }
    }
}

// ---------------- per-pair exp(score) from fused bf16 QK table ----------------
__global__ __launch_bounds__(256) void k_scores(const unsigned short* __restrict__ QKb,
                                                const int* __restrict__ pairs,
                                                const float* __restrict__ agg,
                                                float* __restrict__ es,
                                                float* __restrict__ sumexp,
                                                int* __restrict__ scnt) {
  int wave = threadIdx.x >> 6, lane = threadIdx.x & 63;
  int e = blockIdx.x * 4 + wave;
  int sub = pairs[2 * e], obj = pairs[2 * e + 1];
  short8 q8 = *(const short8*)&QKb[(size_t)sub * 1024 + lane * 8];
  short8 k8 = *(const short8*)&QKb[(size_t)obj * 1024 + 512 + lane * 8];
  float p = 0.f;
  #pragma unroll
  for (int j = 0; j < 8; ++j)
    p += bf2f((unsigned short)q8[j]) * bf2f((unsigned short)k8[j]);
  p += __shfl_xor(p, 1);
  p += __shfl_xor(p, 2);
  p += __shfl_xor(p, 4);
  float ev = expf(p * 0.125f);   // / sqrt(64)
  bool valid = (sub != obj) && (agg[(size_t)sub * N_INST + obj] != 0.f);
  int h = lane >> 3;
  if ((lane & 7) == 0) {
    es[(size_t)e * 8 + h] = valid ? ev : -1.f;
    if (valid) atomicAdd(&sumexp[sub * 8 + h], ev);
  }
  if (lane == 0 && valid) atomicAdd(&scnt[sub], 1);
}

// ---------------- per-row denominators -> invden, base ----------------
__global__ __launch_bounds__(256) void k_denom(const float* __restrict__ sumexp,
                                               const int* __restrict__ scnt,
                                               const int* __restrict__ acnt,
                                               float* __restrict__ invden,
                                               float* __restrict__ base) {
  int i = blockIdx.x * 256 + threadIdx.x;
  if (i >= N_INST) return;
  float c0 = (float)(acnt[i] - scnt[i]);
  const float E0 = expf(1e-7f);
  float bsum = 0.f;
  #pragma unroll
  for (int h = 0; h < NHEAD; ++h) {
    float inv = 1.0f / (E0 + c0 + sumexp[i * NHEAD + h]);
    invden[i * NHEAD + h] = inv;
    bsum += inv;
  }
  base[i] = bsum * (1.0f / NHEAD);
}

// ---------------- scatter ratio entries into mask ----------------
__global__ __launch_bounds__(256) void k_scatter(const int* __restrict__ pairs,
                                                 const float* __restrict__ es,
                                                 const float* __restrict__ invden,
                                                 const float* __restrict__ base,
                                                 unsigned short* __restrict__ maskb) {
  int e = blockIdx.x * 256 + threadIdx.x;
  if (e >= NPAIR) return;
  float4 e0 = *(const float4*)&es[(size_t)e * 8];
  if (e0.x < 0.f) return;
  float4 e1 = *(const float4*)&es[(size_t)e * 8 + 4];
  int sub = pairs[2 * e], obj = pairs[2 * e + 1];
  const float* inv = &invden[sub * 8];
  float f = e0.x * inv[0] + e0.y * inv[1] + e0.z * inv[2] + e0.w * inv[3] +
            e1.x * inv[4] + e1.y * inv[5] + e1.z * inv[6] + e1.w * inv[7];
  maskb[(size_t)sub * N_INST + obj] = f2bf(f * 0.125f / base[sub]);
}

// ---------------- reduce split-K partials + row scale ----------------
__global__ __launch_bounds__(256) void k_redscale(const float* __restrict__ P,
                                                  const float* __restrict__ base,
                                                  float* __restrict__ out) {
  size_t idx = ((size_t)blockIdx.x * 256 + threadIdx.x) * 4;
  int i = (int)(idx >> 9);
  float4 a = *(const float4*)&P[idx];
  float4 b = *(const float4*)&P[idx + (size_t)N_INST * 512];
  float s = base[i];
  float4 o;
  o.x = s * (a.x + b.x); o.y = s * (a.y + b.y);
  o.z = s * (a.z + b.z); o.w = s * (a.w + b.w);
  *(float4*)&out[idx] = o;
}

extern "C" void kernel_launch(void* const* d_in, const int* in_sizes, int n_in,
                              void* d_out, int out_size, void* d_ws, size_t ws_size,
                              hipStream_t stream) {
  const float* x   = (const float*)d_in[0];
  const float* agg = (const float*)d_in[1];
  const int*   prs = (const int*)d_in[2];
  const float* w_q = (const float*)d_in[3];
  const float* b_q = (const float*)d_in[4];
  const float* w_k = (const float*)d_in[5];
  const float* b_k = (const float*)d_in[6];
  float* out = (float*)d_out;

  char* ws = (char*)d_ws;
  size_t off = 0;
  auto alloc = [&](size_t bytes) -> void* {
    void* p = ws + off;
    off += (bytes + 255) & ~(size_t)255;
    return p;
  };
  unsigned short* xb    = (unsigned short*)alloc((size_t)N_INST * D_FEAT * 2);
  unsigned short* xbT   = (unsigned short*)alloc((size_t)D_FEAT * N_INST * 2);
  unsigned short* wqkb  = (unsigned short*)alloc((size_t)1024 * D_FEAT * 2);
  void*           QKP   = alloc((size_t)N_INST * 1024 * 4);   // bf16 QK table, later f32 split-K partials
  float*          es    = (float*)alloc((size_t)NPAIR * NHEAD * 4);
  float*          sumexp= (float*)alloc((size_t)N_INST * NHEAD * 4);
  int*            scnt  = (int*)alloc((size_t)N_INST * 4);
  int*            acnt  = (int*)alloc((size_t)N_INST * 4);
  float*          invden= (float*)alloc((size_t)N_INST * NHEAD * 4);
  float*          base  = (float*)alloc((size_t)N_INST * 4);
  unsigned short* maskb = (unsigned short*)alloc((size_t)N_INST * N_INST * 2);

  hipMemsetAsync(sumexp, 0, (size_t)N_INST * NHEAD * 4, stream);
  hipMemsetAsync(scnt, 0, (size_t)N_INST * 4, stream);

  k_castw<<<dim3(D_FEAT * D_FEAT / 4 / 256, 2), 256, 0, stream>>>(w_q, w_k, wqkb);
  k_xprep<<<dim3(D_FEAT / 32, N_INST / 32), 256, 0, stream>>>(x, xb, xbT);
  k_mask_acnt<<<dim3(N_INST), 256, 0, stream>>>(agg, maskb, acnt);

  // fused Q|K projection: C (4096x1024 bf16) = xb (4096x512) * wqkb (1024x512)^T + bias
  k_gemm<1, 1><<<dim3(1024 / 64, N_INST / 128, 1), 256, 0, stream>>>(
      xb, wqkb, b_q, b_k, QKP, N_INST, 1024, D_FEAT, D_FEAT);

  k_scores<<<dim3(NPAIR / 4), 256, 0, stream>>>((const unsigned short*)QKP, prs, agg, es, sumexp, scnt);
  k_denom<<<dim3(N_INST / 256), 256, 0, stream>>>(sumexp, scnt, acnt, invden, base);
  k_scatter<<<dim3(NPAIR / 256), 256, 0, stream>>>(prs, es, invden, base, maskb);

  // out partials (f32) = maskb (4096x4096) * xbT (512x4096)^T, split-K=2
  k_gemm<0, 0><<<dim3(512 / 64, N_INST / 128, 2), 256, 0, stream>>>(
      maskb, xbT, nullptr, nullptr, QKP, N_INST, 512, N_INST, N_INST / 2);

  k_redscale<<<dim3(N_INST * 512 / 4 / 256), 256, 0, stream>>>((const float*)QKP, base, out);
}

// Round 8
// 124.976 us; speedup vs baseline: 1.1457x; 1.0726x over previous
//
#include <hip/hip_runtime.h>

#define N_INST 4096
#define D_FEAT 512
#define NHEAD 8
#define NPAIR 131072

typedef __attribute__((ext_vector_type(8))) short short8;
typedef __attribute__((ext_vector_type(4))) float f32x4;
typedef __attribute__((ext_vector_type(4))) unsigned short u16x4;

__device__ inline unsigned short f2bf(float f) {
  union { float f; unsigned u; } v; v.f = f;
  unsigned r = v.u + 0x7fffu + ((v.u >> 16) & 1u);
  return (unsigned short)(r >> 16);
}
__device__ inline float bf2f(unsigned short b) {
  union { unsigned u; float f; } v; v.u = ((unsigned)b) << 16; return v.f;
}
__device__ inline void gload16(const void* g, void* l) {
  __builtin_amdgcn_global_load_lds((const __attribute__((address_space(1))) unsigned int*)g,
                                   (__attribute__((address_space(3))) unsigned int*)l, 16, 0, 0);
}

// ---------------- both weight casts in one launch (y=0 -> w_q, y=1 -> w_k) ----------------
__global__ __launch_bounds__(256) void k_castw(const float* __restrict__ wq,
                                               const float* __restrict__ wk,
                                               unsigned short* __restrict__ dst) {
  const float* src = blockIdx.y ? wk : wq;
  unsigned short* d = dst + (size_t)blockIdx.y * D_FEAT * D_FEAT;
  int i = (blockIdx.x * 256 + threadIdx.x) * 4;
  float4 v = *(const float4*)&src[i];
  ushort4 o;
  o.x = f2bf(v.x); o.y = f2bf(v.y); o.z = f2bf(v.z); o.w = f2bf(v.w);
  *(ushort4*)&d[i] = o;
}

// ---------------- x (4096x512 f32) -> xb bf16 AND xT bf16 (512x4096), one read ----------------
__global__ __launch_bounds__(256) void k_xprep(const float* __restrict__ x,
                                               unsigned short* __restrict__ xb,
                                               unsigned short* __restrict__ xT) {
  __shared__ float t[32][33];
  int bx = blockIdx.x, by = blockIdx.y;
  int tx = threadIdx.x & 31, ty = threadIdx.x >> 5;
  #pragma unroll
  for (int r = 0; r < 4; ++r) {
    int row = by * 32 + ty + r * 8;
    float v = x[(size_t)row * D_FEAT + bx * 32 + tx];
    t[ty + r * 8][tx] = v;
    xb[(size_t)row * D_FEAT + bx * 32 + tx] = f2bf(v);
  }
  __syncthreads();
  #pragma unroll
  for (int r = 0; r < 4; ++r)
    xT[(size_t)(bx * 32 + ty + r * 8) * N_INST + by * 32 + tx] = f2bf(t[tx][ty + r * 8]);
}

// ---------------- block-per-row: 0/1 bf16 mask (diag=1) + off-diag count, NT streaming ----------------
__global__ __launch_bounds__(256) void k_mask_acnt(const float* __restrict__ agg,
                                                   unsigned short* __restrict__ maskb,
                                                   int* __restrict__ acnt) {
  int i = blockIdx.x;
  const f32x4* row = (const f32x4*)(agg + (size_t)i * N_INST);
  u16x4* mrow = (u16x4*)(maskb + (size_t)i * N_INST);
  int tid = threadIdx.x;
  f32x4 v[4];
  #pragma unroll
  for (int u = 0; u < 4; ++u)
    v[u] = __builtin_nontemporal_load(&row[u * 256 + tid]);
  int cnt = 0;
  #pragma unroll
  for (int u = 0; u < 4; ++u) {
    int t = u * 256 + tid;
    u16x4 m;
    m[0] = (v[u][0] != 0.f) ? 0x3F80 : 0;
    m[1] = (v[u][1] != 0.f) ? 0x3F80 : 0;
    m[2] = (v[u][2] != 0.f) ? 0x3F80 : 0;
    m[3] = (v[u][3] != 0.f) ? 0x3F80 : 0;
    cnt += (v[u][0] != 0.f) + (v[u][1] != 0.f) + (v[u][2] != 0.f) + (v[u][3] != 0.f);
    int j = t * 4;
    if (i >= j && i < j + 4) {
      int d = i - j;
      m[d] = 0x3F80;                    // diagonal always present
      cnt -= (v[u][d] != 0.f);          // diag not counted as generic
    }
    __builtin_nontemporal_store(m, &mrow[t]);
  }
  #pragma unroll
  for (int msk = 1; msk < 64; msk <<= 1) cnt += __shfl_xor(cnt, msk);
  __shared__ int wsum[4];
  if ((threadIdx.x & 63) == 0) wsum[threadIdx.x >> 6] = cnt;
  __syncthreads();
  if (threadIdx.x == 0) acnt[i] = wsum[0] + wsum[1] + wsum[2] + wsum[3];
}

// ---------------- NT bf16 MFMA GEMM, BM=128, BN templated (64 or 128), BK=64 ----------------
// gload_lds staging + LDS dbuf + granule swizzle + XCD-chunked tile swizzle.
// BN=128: 32 MFMA per 16 ds_read_b128 per wave-iter (halves LDS bytes/FLOP vs BN=64).
template<int BIAS, int CBF16, int BN>
__global__ __launch_bounds__(256, 2) void k_gemm(const unsigned short* __restrict__ A,
                                                 const unsigned short* __restrict__ B,
                                                 const float* __restrict__ bias0,
                                                 const float* __restrict__ bias1,
                                                 void* __restrict__ Cv,
                                                 int M, int N, int K, int klen) {
  constexpr int NI = BN / 32;        // 16-col frags per wave in N
  constexpr int BCH = BN / 32;       // B staging chunks per wave
  __shared__ __align__(16) unsigned short lA[2][128 * 64];
  __shared__ __align__(16) unsigned short lB[2][BN * 64];
  int tid = threadIdx.x, wave = tid >> 6, lane = tid & 63;
  int wm = wave & 1, wn = wave >> 1;
  // --- XCD-chunked bijective swizzle (nxy % 8 == 0 for all our grids) ---
  int gx = gridDim.x;
  int nxy = gx * gridDim.y;
  int lin = blockIdx.x + gx * blockIdx.y;
  int nch = nxy >> 3;
  int nl = (lin & 7) * nch + (lin >> 3);
  int bx = nl % gx, by = nl / gx;
  int bm = by * 128, bn = bx * BN;
  int kbase = blockIdx.z * klen;
  // staging: 1KB chunks = 8 rows x 128B; lane l -> row +l>>3, phys granule l&7.
  // swizzled layout stores logical granule g at phys g^(row&7) -> source granule = (l&7)^(l>>3)
  int srow = lane >> 3;
  int sg = (lane & 7) ^ srow;
  const unsigned short* ag[4];
  const unsigned short* bg[BCH];
  #pragma unroll
  for (int p = 0; p < 4; ++p) {
    int row = (wave * 4 + p) * 8 + srow;
    ag[p] = A + (size_t)(bm + row) * K + kbase + sg * 8;
  }
  #pragma unroll
  for (int p = 0; p < BCH; ++p) {
    int row = (wave * BCH + p) * 8 + srow;
    bg[p] = B + (size_t)(bn + row) * K + kbase + sg * 8;
  }
  auto stage = [&](int buf) {
    #pragma unroll
    for (int p = 0; p < 4; ++p) { gload16(ag[p], &lA[buf][(wave * 4 + p) * 512]); ag[p] += 64; }
    #pragma unroll
    for (int p = 0; p < BCH; ++p) { gload16(bg[p], &lB[buf][(wave * BCH + p) * 512]); bg[p] += 64; }
  };
  f32x4 acc[4][NI] = {};
  int nt = klen / 64;
  stage(0);
  __syncthreads();
  int cur = 0;
  int lrow = lane & 15, glq = lane >> 4;
  for (int t = 0; t < nt; ++t) {
    if (t + 1 < nt) stage(cur ^ 1);
    short8 bf[2][NI];
    #pragma unroll
    for (int kk = 0; kk < 2; ++kk)
      #pragma unroll
      for (int ni = 0; ni < NI; ++ni) {
        int row = wn * (BN / 2) + ni * 16 + lrow;
        int pg = (kk * 4 + glq) ^ (row & 7);
        bf[kk][ni] = *(const short8*)&lB[cur][row * 64 + pg * 8];
      }
    #pragma unroll
    for (int mi = 0; mi < 4; ++mi)
      #pragma unroll
      for (int kk = 0; kk < 2; ++kk) {
        int row = wm * 64 + mi * 16 + lrow;
        int pg = (kk * 4 + glq) ^ (row & 7);
        short8 af = *(const short8*)&lA[cur][row * 64 + pg * 8];
        #pragma unroll
        for (int ni = 0; ni < NI; ++ni)
          acc[mi][ni] = __builtin_amdgcn_mfma_f32_16x16x32_bf16(af, bf[kk][ni], acc[mi][ni], 0, 0, 0);
      }
    __syncthreads();
    cur ^= 1;
  }
  #pragma unroll
  for (int mi = 0; mi < 4; ++mi)
    #pragma unroll
    for (int ni = 0; ni < NI; ++ni) {
      int col = bn + wn * (BN / 2) + ni * 16 + lrow;
      float bv = 0.f;
      if (BIAS) bv = (col < 512) ? bias0[col] : bias1[col - 512];
      #pragma unroll
      for (int j = 0; j < 4; ++j) {
        int row = bm + wm * 64 + mi * 16 + glq * 4 + j;
        float vv = acc[mi][ni][j] + bv;
        if (CBF16) {
          ((unsigned short*)Cv)[(size_t)row * N + col] = f2bf(vv);
        } else {
          float* C = (float*)Cv + (size_t)blockIdx.z * M * N;
          C[(size_t)row * N + col] = vv;
        }
      }
    }
}

// ---------------- per-pair exp(score) from fused bf16 QK table ----------------
__global__ __launch_bounds__(256) void k_scores(const unsigned short* __restrict__ QKb,
                                                const int* __restrict__ pairs,
                                                const float* __restrict__ agg,
                                                float* __restrict__ es,
                                                float* __restrict__ sumexp,
                                                int* __restrict__ scnt) {
  int wave = threadIdx.x >> 6, lane = threadIdx.x & 63;
  int e = blockIdx.x * 4 + wave;
  int sub = pairs[2 * e], obj = pairs[2 * e + 1];
  short8 q8 = *(const short8*)&QKb[(size_t)sub * 1024 + lane * 8];
  short8 k8 = *(const short8*)&QKb[(size_t)obj * 1024 + 512 + lane * 8];
  float p = 0.f;
  #pragma unroll
  for (int j = 0; j < 8; ++j)
    p += bf2f((unsigned short)q8[j]) * bf2f((unsigned short)k8[j]);
  p += __shfl_xor(p, 1);
  p += __shfl_xor(p, 2);
  p += __shfl_xor(p, 4);
  float ev = expf(p * 0.125f);   // / sqrt(64)
  bool valid = (sub != obj) && (agg[(size_t)sub * N_INST + obj] != 0.f);
  int h = lane >> 3;
  if ((lane & 7) == 0) {
    es[(size_t)e * 8 + h] = valid ? ev : -1.f;
    if (valid) atomicAdd(&sumexp[sub * 8 + h], ev);
  }
  if (lane == 0 && valid) atomicAdd(&scnt[sub], 1);
}

// ---------------- per-row denominators -> invden, base ----------------
__global__ __launch_bounds__(256) void k_denom(const float* __restrict__ sumexp,
                                               const int* __restrict__ scnt,
                                               const int* __restrict__ acnt,
                                               float* __restrict__ invden,
                                               float* __restrict__ base) {
  int i = blockIdx.x * 256 + threadIdx.x;
  if (i >= N_INST) return;
  float c0 = (float)(acnt[i] - scnt[i]);
  const float E0 = expf(1e-7f);
  float bsum = 0.f;
  #pragma unroll
  for (int h = 0; h < NHEAD; ++h) {
    float inv = 1.0f / (E0 + c0 + sumexp[i * NHEAD + h]);
    invden[i * NHEAD + h] = inv;
    bsum += inv;
  }
  base[i] = bsum * (1.0f / NHEAD);
}

// ---------------- scatter ratio entries into mask ----------------
__global__ __launch_bounds__(256) void k_scatter(const int* __restrict__ pairs,
                                                 const float* __restrict__ es,
                                                 const float* __restrict__ invden,
                                                 const float* __restrict__ base,
                                                 unsigned short* __restrict__ maskb) {
  int e = blockIdx.x * 256 + threadIdx.x;
  if (e >= NPAIR) return;
  float4 e0 = *(const float4*)&es[(size_t)e * 8];
  if (e0.x < 0.f) return;
  float4 e1 = *(const float4*)&es[(size_t)e * 8 + 4];
  int sub = pairs[2 * e], obj = pairs[2 * e + 1];
  const float* inv = &invden[sub * 8];
  float f = e0.x * inv[0] + e0.y * inv[1] + e0.z * inv[2] + e0.w * inv[3] +
            e1.x * inv[4] + e1.y * inv[5] + e1.z * inv[6] + e1.w * inv[7];
  maskb[(size_t)sub * N_INST + obj] = f2bf(f * 0.125f / base[sub]);
}

// ---------------- reduce split-K=4 partials + row scale ----------------
__global__ __launch_bounds__(256) void k_redscale(const float* __restrict__ P,
                                                  const float* __restrict__ base,
                                                  float* __restrict__ out) {
  size_t idx = ((size_t)blockIdx.x * 256 + threadIdx.x) * 4;
  int i = (int)(idx >> 9);
  const size_t S = (size_t)N_INST * 512;
  float4 a = *(const float4*)&P[idx];
  float4 b = *(const float4*)&P[idx + S];
  float4 c = *(const float4*)&P[idx + 2 * S];
  float4 d = *(const float4*)&P[idx + 3 * S];
  float s = base[i];
  float4 o;
  o.x = s * (a.x + b.x + c.x + d.x);
  o.y = s * (a.y + b.y + c.y + d.y);
  o.z = s * (a.z + b.z + c.z + d.z);
  o.w = s * (a.w + b.w + c.w + d.w);
  *(float4*)&out[idx] = o;
}

extern "C" void kernel_launch(void* const* d_in, const int* in_sizes, int n_in,
                              void* d_out, int out_size, void* d_ws, size_t ws_size,
                              hipStream_t stream) {
  const float* x   = (const float*)d_in[0];
  const float* agg = (const float*)d_in[1];
  const int*   prs = (const int*)d_in[2];
  const float* w_q = (const float*)d_in[3];
  const float* b_q = (const float*)d_in[4];
  const float* w_k = (const float*)d_in[5];
  const float* b_k = (const float*)d_in[6];
  float* out = (float*)d_out;

  char* ws = (char*)d_ws;
  size_t off = 0;
  auto alloc = [&](size_t bytes) -> void* {
    void* p = ws + off;
    off += (bytes + 255) & ~(size_t)255;
    return p;
  };
  unsigned short* xb    = (unsigned short*)alloc((size_t)N_INST * D_FEAT * 2);
  unsigned short* xbT   = (unsigned short*)alloc((size_t)D_FEAT * N_INST * 2);
  unsigned short* wqkb  = (unsigned short*)alloc((size_t)1024 * D_FEAT * 2);
  void*           QKP   = alloc((size_t)N_INST * 512 * 4 * 4);  // bf16 QK table (8MB), later 4x f32 split-K partials (32MB)
  float*          es    = (float*)alloc((size_t)NPAIR * NHEAD * 4);
  float*          sumexp= (float*)alloc((size_t)N_INST * NHEAD * 4);
  int*            scnt  = (int*)alloc((size_t)N_INST * 4);
  int*            acnt  = (int*)alloc((size_t)N_INST * 4);
  float*          invden= (float*)alloc((size_t)N_INST * NHEAD * 4);
  float*          base  = (float*)alloc((size_t)N_INST * 4);
  unsigned short* maskb = (unsigned short*)alloc((size_t)N_INST * N_INST * 2);

  hipMemsetAsync(sumexp, 0, (size_t)N_INST * NHEAD * 4, stream);
  hipMemsetAsync(scnt, 0, (size_t)N_INST * 4, stream);

  k_castw<<<dim3(D_FEAT * D_FEAT / 4 / 256, 2), 256, 0, stream>>>(w_q, w_k, wqkb);
  k_xprep<<<dim3(D_FEAT / 32, N_INST / 32), 256, 0, stream>>>(x, xb, xbT);
  k_mask_acnt<<<dim3(N_INST), 256, 0, stream>>>(agg, maskb, acnt);

  // fused Q|K projection: C (4096x1024 bf16) = xb (4096x512) * wqkb (1024x512)^T + bias
  k_gemm<1, 1, 64><<<dim3(1024 / 64, N_INST / 128, 1), 256, 0, stream>>>(
      xb, wqkb, b_q, b_k, QKP, N_INST, 1024, D_FEAT, D_FEAT);

  k_scores<<<dim3(NPAIR / 4), 256, 0, stream>>>((const unsigned short*)QKP, prs, agg, es, sumexp, scnt);
  k_denom<<<dim3(N_INST / 256), 256, 0, stream>>>(sumexp, scnt, acnt, invden, base);
  k_scatter<<<dim3(NPAIR / 256), 256, 0, stream>>>(prs, es, invden, base, maskb);

  // out partials (f32) = maskb (4096x4096) * xbT (512x4096)^T, 128x128 tile, split-K=4
  k_gemm<0, 0, 128><<<dim3(512 / 128, N_INST / 128, 4), 256, 0, stream>>>(
      maskb, xbT, nullptr, nullptr, QKP, N_INST, 512, N_INST, N_INST / 4);

  k_redscale<<<dim3(N_INST * 512 / 4 / 256), 256, 0, stream>>>((const float*)QKP, base, out);
}

// Round 9
// 120.800 us; speedup vs baseline: 1.1853x; 1.0346x over previous
//
#include <hip/hip_runtime.h>

#define N_INST 4096
#define D_FEAT 512
#define NHEAD 8
#define NPAIR 131072

typedef __attribute__((ext_vector_type(8))) short short8;
typedef __attribute__((ext_vector_type(4))) float f32x4;
typedef __attribute__((ext_vector_type(4))) unsigned short u16x4;

__device__ inline unsigned short f2bf(float f) {
  union { float f; unsigned u; } v; v.f = f;
  unsigned r = v.u + 0x7fffu + ((v.u >> 16) & 1u);
  return (unsigned short)(r >> 16);
}
__device__ inline float bf2f(unsigned short b) {
  union { unsigned u; float f; } v; v.u = ((unsigned)b) << 16; return v.f;
}
__device__ inline void gload16(const void* g, void* l) {
  __builtin_amdgcn_global_load_lds((const __attribute__((address_space(1))) unsigned int*)g,
                                   (__attribute__((address_space(3))) unsigned int*)l, 16, 0, 0);
}

// ---------------- both weight casts in one launch (y=0 -> w_q, y=1 -> w_k) ----------------
__global__ __launch_bounds__(256) void k_castw(const float* __restrict__ wq,
                                               const float* __restrict__ wk,
                                               unsigned short* __restrict__ dst) {
  const float* src = blockIdx.y ? wk : wq;
  unsigned short* d = dst + (size_t)blockIdx.y * D_FEAT * D_FEAT;
  int i = (blockIdx.x * 256 + threadIdx.x) * 4;
  float4 v = *(const float4*)&src[i];
  ushort4 o;
  o.x = f2bf(v.x); o.y = f2bf(v.y); o.z = f2bf(v.z); o.w = f2bf(v.w);
  *(ushort4*)&d[i] = o;
}

// ---------------- x (4096x512 f32) -> xb bf16 AND xT bf16 (512x4096), one read ----------------
__global__ __launch_bounds__(256) void k_xprep(const float* __restrict__ x,
                                               unsigned short* __restrict__ xb,
                                               unsigned short* __restrict__ xT) {
  __shared__ float t[32][33];
  int bx = blockIdx.x, by = blockIdx.y;
  int tx = threadIdx.x & 31, ty = threadIdx.x >> 5;
  #pragma unroll
  for (int r = 0; r < 4; ++r) {
    int row = by * 32 + ty + r * 8;
    float v = x[(size_t)row * D_FEAT + bx * 32 + tx];
    t[ty + r * 8][tx] = v;
    xb[(size_t)row * D_FEAT + bx * 32 + tx] = f2bf(v);
  }
  __syncthreads();
  #pragma unroll
  for (int r = 0; r < 4; ++r)
    xT[(size_t)(bx * 32 + ty + r * 8) * N_INST + by * 32 + tx] = f2bf(t[tx][ty + r * 8]);
}

// ---------------- block-per-row: 0/1 bf16 mask (diag=1) + off-diag count, NT streaming ----------------
__global__ __launch_bounds__(256) void k_mask_acnt(const float* __restrict__ agg,
                                                   unsigned short* __restrict__ maskb,
                                                   int* __restrict__ acnt) {
  int i = blockIdx.x;
  const f32x4* row = (const f32x4*)(agg + (size_t)i * N_INST);
  u16x4* mrow = (u16x4*)(maskb + (size_t)i * N_INST);
  int tid = threadIdx.x;
  f32x4 v[4];
  #pragma unroll
  for (int u = 0; u < 4; ++u)
    v[u] = __builtin_nontemporal_load(&row[u * 256 + tid]);
  int cnt = 0;
  #pragma unroll
  for (int u = 0; u < 4; ++u) {
    int t = u * 256 + tid;
    u16x4 m;
    m[0] = (v[u][0] != 0.f) ? 0x3F80 : 0;
    m[1] = (v[u][1] != 0.f) ? 0x3F80 : 0;
    m[2] = (v[u][2] != 0.f) ? 0x3F80 : 0;
    m[3] = (v[u][3] != 0.f) ? 0x3F80 : 0;
    cnt += (v[u][0] != 0.f) + (v[u][1] != 0.f) + (v[u][2] != 0.f) + (v[u][3] != 0.f);
    int j = t * 4;
    if (i >= j && i < j + 4) {
      int d = i - j;
      m[d] = 0x3F80;                    // diagonal always present
      cnt -= (v[u][d] != 0.f);          // diag not counted as generic
    }
    __builtin_nontemporal_store(m, &mrow[t]);
  }
  #pragma unroll
  for (int msk = 1; msk < 64; msk <<= 1) cnt += __shfl_xor(cnt, msk);
  __shared__ int wsum[4];
  if ((threadIdx.x & 63) == 0) wsum[threadIdx.x >> 6] = cnt;
  __syncthreads();
  if (threadIdx.x == 0) acnt[i] = wsum[0] + wsum[1] + wsum[2] + wsum[3];
}

// ---------------- NT bf16 MFMA GEMM, BM=128, BN templated (64 or 128), BK=64 ----------------
// gload_lds staging + LDS dbuf + granule swizzle + XCD-chunked tile swizzle.
template<int BIAS, int CBF16, int BN>
__global__ __launch_bounds__(256, 2) void k_gemm(const unsigned short* __restrict__ A,
                                                 const unsigned short* __restrict__ B,
                                                 const float* __restrict__ bias0,
                                                 const float* __restrict__ bias1,
                                                 void* __restrict__ Cv,
                                                 int M, int N, int K, int klen) {
  constexpr int NI = BN / 32;        // 16-col frags per wave in N
  constexpr int BCH = BN / 32;       // B staging chunks per wave
  __shared__ __align__(16) unsigned short lA[2][128 * 64];
  __shared__ __align__(16) unsigned short lB[2][BN * 64];
  int tid = threadIdx.x, wave = tid >> 6, lane = tid & 63;
  int wm = wave & 1, wn = wave >> 1;
  // --- XCD-chunked bijective swizzle (nxy % 8 == 0 for all our grids) ---
  int gx = gridDim.x;
  int nxy = gx * gridDim.y;
  int lin = blockIdx.x + gx * blockIdx.y;
  int nch = nxy >> 3;
  int nl = (lin & 7) * nch + (lin >> 3);
  int bx = nl % gx, by = nl / gx;
  int bm = by * 128, bn = bx * BN;
  int kbase = blockIdx.z * klen;
  // staging: 1KB chunks = 8 rows x 128B; lane l -> row +l>>3, phys granule l&7.
  // swizzled layout stores logical granule g at phys g^(row&7) -> source granule = (l&7)^(l>>3)
  int srow = lane >> 3;
  int sg = (lane & 7) ^ srow;
  const unsigned short* ag[4];
  const unsigned short* bg[BCH];
  #pragma unroll
  for (int p = 0; p < 4; ++p) {
    int row = (wave * 4 + p) * 8 + srow;
    ag[p] = A + (size_t)(bm + row) * K + kbase + sg * 8;
  }
  #pragma unroll
  for (int p = 0; p < BCH; ++p) {
    int row = (wave * BCH + p) * 8 + srow;
    bg[p] = B + (size_t)(bn + row) * K + kbase + sg * 8;
  }
  auto stage = [&](int buf) {
    #pragma unroll
    for (int p = 0; p < 4; ++p) { gload16(ag[p], &lA[buf][(wave * 4 + p) * 512]); ag[p] += 64; }
    #pragma unroll
    for (int p = 0; p < BCH; ++p) { gload16(bg[p], &lB[buf][(wave * BCH + p) * 512]); bg[p] += 64; }
  };
  f32x4 acc[4][NI] = {};
  int nt = klen / 64;
  stage(0);
  __syncthreads();
  int cur = 0;
  int lrow = lane & 15, glq = lane >> 4;
  for (int t = 0; t < nt; ++t) {
    if (t + 1 < nt) stage(cur ^ 1);
    short8 bf[2][NI];
    #pragma unroll
    for (int kk = 0; kk < 2; ++kk)
      #pragma unroll
      for (int ni = 0; ni < NI; ++ni) {
        int row = wn * (BN / 2) + ni * 16 + lrow;
        int pg = (kk * 4 + glq) ^ (row & 7);
        bf[kk][ni] = *(const short8*)&lB[cur][row * 64 + pg * 8];
      }
    #pragma unroll
    for (int mi = 0; mi < 4; ++mi)
      #pragma unroll
      for (int kk = 0; kk < 2; ++kk) {
        int row = wm * 64 + mi * 16 + lrow;
        int pg = (kk * 4 + glq) ^ (row & 7);
        short8 af = *(const short8*)&lA[cur][row * 64 + pg * 8];
        #pragma unroll
        for (int ni = 0; ni < NI; ++ni)
          acc[mi][ni] = __builtin_amdgcn_mfma_f32_16x16x32_bf16(af, bf[kk][ni], acc[mi][ni], 0, 0, 0);
      }
    __syncthreads();
    cur ^= 1;
  }
  #pragma unroll
  for (int mi = 0; mi < 4; ++mi)
    #pragma unroll
    for (int ni = 0; ni < NI; ++ni) {
      int col = bn + wn * (BN / 2) + ni * 16 + lrow;
      float bv = 0.f;
      if (BIAS) bv = (col < 512) ? bias0[col] : bias1[col - 512];
      #pragma unroll
      for (int j = 0; j < 4; ++j) {
        int row = bm + wm * 64 + mi * 16 + glq * 4 + j;
        float vv = acc[mi][ni][j] + bv;
        if (CBF16) {
          ((unsigned short*)Cv)[(size_t)row * N + col] = f2bf(vv);
        } else {
          float* C = (float*)Cv + (size_t)blockIdx.z * M * N;
          C[(size_t)row * N + col] = vv;
        }
      }
    }
}

// ---------------- per-pair exp(score): validity-first early exit ----------------
// ~50% of pairs are invalid (agg==0 or diag) and never contribute to the
// softmax (reference overwrites them with -inf/diag). Check validity with one
// wave-uniform 4B load and retire the wave BEFORE the 2KB Q/K gather.
__global__ __launch_bounds__(256) void k_scores(const unsigned short* __restrict__ QKb,
                                                const int* __restrict__ pairs,
                                                const float* __restrict__ agg,
                                                float* __restrict__ es,
                                                float* __restrict__ sumexp,
                                                int* __restrict__ scnt) {
  int wave = threadIdx.x >> 6, lane = threadIdx.x & 63;
  int e = blockIdx.x * 4 + wave;
  int2 pr = *(const int2*)&pairs[2 * e];
  int sub = pr.x, obj = pr.y;
  bool valid = (sub != obj) && (agg[(size_t)sub * N_INST + obj] != 0.f);
  if (!valid) {
    if (lane == 0) es[(size_t)e * 8] = -1.f;
    return;
  }
  short8 q8 = *(const short8*)&QKb[(size_t)sub * 1024 + lane * 8];
  short8 k8 = *(const short8*)&QKb[(size_t)obj * 1024 + 512 + lane * 8];
  float p = 0.f;
  #pragma unroll
  for (int j = 0; j < 8; ++j)
    p += bf2f((unsigned short)q8[j]) * bf2f((unsigned short)k8[j]);
  p += __shfl_xor(p, 1);
  p += __shfl_xor(p, 2);
  p += __shfl_xor(p, 4);
  float ev = expf(p * 0.125f);   // / sqrt(64)
  int h = lane >> 3;
  if ((lane & 7) == 0) {
    es[(size_t)e * 8 + h] = ev;
    atomicAdd(&sumexp[sub * 8 + h], ev);
  }
  if (lane == 0) atomicAdd(&scnt[sub], 1);
}

// ---------------- per-row denominators -> invden, base ----------------
__global__ __launch_bounds__(256) void k_denom(const float* __restrict__ sumexp,
                                               const int* __restrict__ scnt,
                                               const int* __restrict__ acnt,
                                               float* __restrict__ invden,
                                               float* __restrict__ base) {
  int i = blockIdx.x * 256 + threadIdx.x;
  if (i >= N_INST) return;
  float c0 = (float)(acnt[i] - scnt[i]);
  const float E0 = expf(1e-7f);
  float bsum = 0.f;
  #pragma unroll
  for (int h = 0; h < NHEAD; ++h) {
    float inv = 1.0f / (E0 + c0 + sumexp[i * NHEAD + h]);
    invden[i * NHEAD + h] = inv;
    bsum += inv;
  }
  base[i] = bsum * (1.0f / NHEAD);
}

// ---------------- scatter ratio entries into mask ----------------
__global__ __launch_bounds__(256) void k_scatter(const int* __restrict__ pairs,
                                                 const float* __restrict__ es,
                                                 const float* __restrict__ invden,
                                                 const float* __restrict__ base,
                                                 unsigned short* __restrict__ maskb) {
  int e = blockIdx.x * 256 + threadIdx.x;
  if (e >= NPAIR) return;
  float4 e0 = *(const float4*)&es[(size_t)e * 8];
  if (e0.x < 0.f) return;
  float4 e1 = *(const float4*)&es[(size_t)e * 8 + 4];
  int sub = pairs[2 * e], obj = pairs[2 * e + 1];
  const float* inv = &invden[sub * 8];
  float f = e0.x * inv[0] + e0.y * inv[1] + e0.z * inv[2] + e0.w * inv[3] +
            e1.x * inv[4] + e1.y * inv[5] + e1.z * inv[6] + e1.w * inv[7];
  maskb[(size_t)sub * N_INST + obj] = f2bf(f * 0.125f / base[sub]);
}

// ---------------- reduce split-K=4 partials + row scale ----------------
__global__ __launch_bounds__(256) void k_redscale(const float* __restrict__ P,
                                                  const float* __restrict__ base,
                                                  float* __restrict__ out) {
  size_t idx = ((size_t)blockIdx.x * 256 + threadIdx.x) * 4;
  int i = (int)(idx >> 9);
  const size_t S = (size_t)N_INST * 512;
  float4 a = *(const float4*)&P[idx];
  float4 b = *(const float4*)&P[idx + S];
  float4 c = *(const float4*)&P[idx + 2 * S];
  float4 d = *(const float4*)&P[idx + 3 * S];
  float s = base[i];
  float4 o;
  o.x = s * (a.x + b.x + c.x + d.x);
  o.y = s * (a.y + b.y + c.y + d.y);
  o.z = s * (a.z + b.z + c.z + d.z);
  o.w = s * (a.w + b.w + c.w + d.w);
  *(float4*)&out[idx] = o;
}

extern "C" void kernel_launch(void* const* d_in, const int* in_sizes, int n_in,
                              void* d_out, int out_size, void* d_ws, size_t ws_size,
                              hipStream_t stream) {
  const float* x   = (const float*)d_in[0];
  const float* agg = (const float*)d_in[1];
  const int*   prs = (const int*)d_in[2];
  const float* w_q = (const float*)d_in[3];
  const float* b_q = (const float*)d_in[4];
  const float* w_k = (const float*)d_in[5];
  const float* b_k = (const float*)d_in[6];
  float* out = (float*)d_out;

  char* ws = (char*)d_ws;
  size_t off = 0;
  auto alloc = [&](size_t bytes) -> void* {
    void* p = ws + off;
    off += (bytes + 255) & ~(size_t)255;
    return p;
  };
  unsigned short* xb    = (unsigned short*)alloc((size_t)N_INST * D_FEAT * 2);
  unsigned short* xbT   = (unsigned short*)alloc((size_t)D_FEAT * N_INST * 2);
  unsigned short* wqkb  = (unsigned short*)alloc((size_t)1024 * D_FEAT * 2);
  void*           QKP   = alloc((size_t)N_INST * 512 * 4 * 4);  // bf16 QK table (8MB), later 4x f32 split-K partials (32MB)
  float*          es    = (float*)alloc((size_t)NPAIR * NHEAD * 4);
  float*          sumexp= (float*)alloc((size_t)N_INST * NHEAD * 4);
  int*            scnt  = (int*)alloc((size_t)N_INST * 4);
  int*            acnt  = (int*)alloc((size_t)N_INST * 4);
  float*          invden= (float*)alloc((size_t)N_INST * NHEAD * 4);
  float*          base  = (float*)alloc((size_t)N_INST * 4);
  unsigned short* maskb = (unsigned short*)alloc((size_t)N_INST * N_INST * 2);

  hipMemsetAsync(sumexp, 0, (size_t)N_INST * NHEAD * 4, stream);
  hipMemsetAsync(scnt, 0, (size_t)N_INST * 4, stream);

  k_castw<<<dim3(D_FEAT * D_FEAT / 4 / 256, 2), 256, 0, stream>>>(w_q, w_k, wqkb);
  k_xprep<<<dim3(D_FEAT / 32, N_INST / 32), 256, 0, stream>>>(x, xb, xbT);
  k_mask_acnt<<<dim3(N_INST), 256, 0, stream>>>(agg, maskb, acnt);

  // fused Q|K projection: C (4096x1024 bf16) = xb (4096x512) * wqkb (1024x512)^T + bias
  k_gemm<1, 1, 64><<<dim3(1024 / 64, N_INST / 128, 1), 256, 0, stream>>>(
      xb, wqkb, b_q, b_k, QKP, N_INST, 1024, D_FEAT, D_FEAT);

  k_scores<<<dim3(NPAIR / 4), 256, 0, stream>>>((const unsigned short*)QKP, prs, agg, es, sumexp, scnt);
  k_denom<<<dim3(N_INST / 256), 256, 0, stream>>>(sumexp, scnt, acnt, invden, base);
  k_scatter<<<dim3(NPAIR / 256), 256, 0, stream>>>(prs, es, invden, base, maskb);

  // out partials (f32) = maskb (4096x4096) * xbT (512x4096)^T, 128x128 tile, split-K=4
  k_gemm<0, 0, 128><<<dim3(512 / 128, N_INST / 128, 4), 256, 0, stream>>>(
      maskb, xbT, nullptr, nullptr, QKP, N_INST, 512, N_INST, N_INST / 4);

  k_redscale<<<dim3(N_INST * 512 / 4 / 256), 256, 0, stream>>>((const float*)QKP, base, out);
}